// Round 6
// baseline (100.932 us; speedup 1.0000x reference)
//
#include <hip/hip_runtime.h>

// smartorn layer: out[b,j] = elu(power[j] * sum_i x[b,i]*gate(i,j) - bias[j])
// gate(i,j) = strength(dpb . outdir_i) * strength(dpb . indir_j)
//   dp = pos_j - pos_i, dpb = dp / sqrt(max(|dp|^2, 1e-5))
//   strength(v) = (exp(v) - e^-1) / (e - e^-1)
//
// R6 = R5 with DOUBLED launches (phase1 x2, phase2 x2) as a differential
// timing probe: both kernels are idempotent (phase1 rewrites the same part
// deterministically, phase2 the same out), so correctness is unchanged and
// dur_R6 - dur_R5 = p1 + p2 exactly. Distinguishes "harness fill floor
// ~75us, kernels ~8us" (dur -> ~91) from "phase1 is 4x over cycle model"
// (dur -> ~113). Kernels byte-identical to R5.

#define NN 4096
#define NB 8
#define RJ 4                 // j per lane
#define JTILE 256            // j per block (= 64 lanes * RJ)
#define IPB 64               // i per block chunk
#define IPW 16               // i per wave (4 waves split the chunk)
#define NSLAB (NN / IPB)     // 64 deterministic i-slabs

typedef __attribute__((ext_vector_type(2))) float f2;

__global__ __launch_bounds__(256, 4) void smartorn_phase1(
    const float* __restrict__ x,       // (B, N)
    const float* __restrict__ pos,     // (N, 3)
    const float* __restrict__ indir,   // (N, 3)
    const float* __restrict__ outdir,  // (N, 3)
    float* __restrict__ part)          // (NSLAB, B, N)
{
    __shared__ float4 srec[IPB * 4];           // 4 KB: 64 B per i-record
    __shared__ float  sacc[4][NB][JTILE];      // 32 KB: per-wave partials

    const int bI   = blockIdx.x;
    const int jt   = bI >> 6;    // 0..15  j-tile
    const int is   = bI & 63;    // 0..63  i-slab
    const int tid  = threadIdx.x;
    const int lane = tid & 63;
    const int w    = __builtin_amdgcn_readfirstlane(tid >> 6);

    // ---- stage the block's 64 i-records (thread t -> record t/4, quad t%4) ----
    {
        const int r  = tid >> 2;
        const int q  = tid & 3;
        const int gi = is * IPB + r;
        float4 v;
        if (q == 0)
            v = make_float4(pos[gi * 3 + 0], pos[gi * 3 + 1], pos[gi * 3 + 2],
                            outdir[gi * 3 + 0]);
        else if (q == 1)
            v = make_float4(outdir[gi * 3 + 1], outdir[gi * 3 + 2],
                            x[0 * NN + gi], x[1 * NN + gi]);
        else if (q == 2)
            v = make_float4(x[2 * NN + gi], x[3 * NN + gi],
                            x[4 * NN + gi], x[5 * NN + gi]);
        else
            v = make_float4(x[6 * NN + gi], x[7 * NN + gi], 0.f, 0.f);
        srec[r * 4 + q] = v;
    }

    // ---- per-lane j-state: RJ receivers ----
    float pjx[RJ], pjy[RJ], pjz[RJ], inx[RJ], iny[RJ], inz[RJ];
#pragma unroll
    for (int r = 0; r < RJ; ++r) {
        const int jg = jt * JTILE + r * 64 + lane;
        pjx[r] = pos[jg * 3 + 0];
        pjy[r] = pos[jg * 3 + 1];
        pjz[r] = pos[jg * 3 + 2];
        inx[r] = indir[jg * 3 + 0];
        iny[r] = indir[jg * 3 + 1];
        inz[r] = indir[jg * 3 + 2];
    }

    __syncthreads();

    f2 acc[RJ][4];
#pragma unroll
    for (int r = 0; r < RJ; ++r)
#pragma unroll
        for (int k = 0; k < 4; ++k) acc[r][k] = (f2){0.f, 0.f};

    const float C1 = 0.36787944117144233f;  // e^-1
    const float SC = 0.18101541533756566f;  // 1 / (e - e^-1)^2

    const float4* S = &srec[w * IPW * 4];   // wave-uniform base -> broadcast reads

#pragma unroll 2
    for (int s = 0; s < IPW; ++s) {
        const float4 q0 = S[s * 4 + 0];   // {px, py, pz, ox}
        const float4 q1 = S[s * 4 + 1];   // {oy, oz, x0, x1}
        const float4 q2 = S[s * 4 + 2];   // {x2, x3, x4, x5}
        const float4 q3 = S[s * 4 + 3];   // {x6, x7, -, -}

#pragma unroll
        for (int r = 0; r < RJ; ++r) {
            const float dx = pjx[r] - q0.x;
            const float dy = pjy[r] - q0.y;
            const float dz = pjz[r] - q0.z;
            float n2 = fmaf(dx, dx, fmaf(dy, dy, dz * dz));
            n2 = fmaxf(n2, 1e-5f);
            const float inv = rsqrtf(n2);
            const float da = fmaf(dx, q0.w, fmaf(dy, q1.x, dz * q1.y)) * inv;
            const float db = fmaf(dx, inx[r], fmaf(dy, iny[r], dz * inz[r])) * inv;
            const float g = (__expf(da) - C1) * (__expf(db) - C1) * SC;
            const f2 gv = {g, g};
            acc[r][0] = __builtin_elementwise_fma((f2){q1.z, q1.w}, gv, acc[r][0]);
            acc[r][1] = __builtin_elementwise_fma((f2){q2.x, q2.y}, gv, acc[r][1]);
            acc[r][2] = __builtin_elementwise_fma((f2){q2.z, q2.w}, gv, acc[r][2]);
            acc[r][3] = __builtin_elementwise_fma((f2){q3.x, q3.y}, gv, acc[r][3]);
        }
    }

    // ---- dump per-wave partials (stride-1 across lanes: conflict-free) ----
#pragma unroll
    for (int r = 0; r < RJ; ++r) {
        const int jp = r * 64 + lane;
#pragma unroll
        for (int k = 0; k < 4; ++k) {
            sacc[w][2 * k + 0][jp] = acc[r][k].x;
            sacc[w][2 * k + 1][jp] = acc[r][k].y;
        }
    }
    __syncthreads();

    // ---- cross-wave reduce, write slab (coalesced 256-wide) ----
#pragma unroll
    for (int b = 0; b < NB; ++b) {
        const float s = sacc[0][b][tid] + sacc[1][b][tid] +
                        sacc[2][b][tid] + sacc[3][b][tid];
        part[(is * NB + b) * NN + jt * JTILE + tid] = s;
    }
}

__global__ __launch_bounds__(256) void smartorn_phase2(
    const float* __restrict__ part,    // (NSLAB, B, N)
    const float* __restrict__ power,   // (N)
    const float* __restrict__ bias,    // (N)
    float* __restrict__ out)           // (B, N)
{
    const int t = blockIdx.x * 256 + threadIdx.x;   // 0 .. B*N-1
    const int j = t & (NN - 1);
    const int b = t >> 12;
    float s = 0.f;
#pragma unroll 16
    for (int is = 0; is < NSLAB; ++is)
        s += part[(is * NB + b) * NN + j];
    const float v = fmaf(s, power[j], -bias[j]);
    out[t] = v > 0.f ? v : expm1f(v);
}

extern "C" void kernel_launch(void* const* d_in, const int* in_sizes, int n_in,
                              void* d_out, int out_size, void* d_ws, size_t ws_size,
                              hipStream_t stream) {
    const float* x      = (const float*)d_in[0];
    const float* pos    = (const float*)d_in[1];
    const float* indir  = (const float*)d_in[2];
    const float* outdir = (const float*)d_in[3];
    const float* power  = (const float*)d_in[4];
    const float* bias   = (const float*)d_in[5];
    float* part = (float*)d_ws;          // NSLAB*B*N*4 = 8 MiB
    float* out  = (float*)d_out;

    dim3 block(256);
    // x2 launches: differential timing probe (idempotent, correctness unchanged)
    hipLaunchKernelGGL(smartorn_phase1, dim3((NN / JTILE) * NSLAB), block, 0, stream,
                       x, pos, indir, outdir, part);
    hipLaunchKernelGGL(smartorn_phase1, dim3((NN / JTILE) * NSLAB), block, 0, stream,
                       x, pos, indir, outdir, part);
    hipLaunchKernelGGL(smartorn_phase2, dim3((NB * NN) / 256), block, 0, stream,
                       part, power, bias, out);
    hipLaunchKernelGGL(smartorn_phase2, dim3((NB * NN) / 256), block, 0, stream,
                       part, power, bias, out);
}

// Round 7
// 83.665 us; speedup vs baseline: 1.2064x; 1.2064x over previous
//
#include <hip/hip_runtime.h>

// smartorn layer: out[b,j] = elu(power[j] * sum_i x[b,i]*gate(i,j) - bias[j])
// gate(i,j) = strength(dpb . outdir_i) * strength(dpb . indir_j)
//   dp = pos_j - pos_i, dpb = dp / sqrt(max(|dp|^2, 1e-5))
//   strength(v) = (exp(v) - e^-1) / (e - e^-1)
//
// R6 differential probe: harness floor ~65us (256MiB ws poison fills),
// kernels ~16-18us (p1 ~12, p2 ~3). R7: attack p1's transcendental block.
// da,db in [-1,1] -> replace both v_exp_f32 with deg-6 Taylor polynomials,
// all constants folded: coeffs scaled by s=sqrt(SC), c0 absorbs -C1*s, so
// gate = Ea*Eb with ONE mul. Removes 2 exp + 2 mul + 2 sub + 1 mul per pair,
// adds 12 fma. Single launches (probe reverted). Structure otherwise R5:
// 4 j/lane, broadcast ds_read_b128 i-records, 64 det. i-slabs, no fences.

#define NN 4096
#define NB 8
#define RJ 4                 // j per lane
#define JTILE 256            // j per block (= 64 lanes * RJ)
#define IPB 64               // i per block chunk
#define IPW 16               // i per wave (4 waves split the chunk)
#define NSLAB (NN / IPB)     // 64 deterministic i-slabs

typedef __attribute__((ext_vector_type(2))) float f2;

// E(v) = s*(exp(v) - C1), s = sqrt(1/(e - e^-1)^2), C1 = e^-1
// gate = E(da)*E(db).  Taylor deg-6 coeffs scaled by s; c0 = s*(1 - C1).
#define PC0 0.26894189f      // s*(1 - e^-1)
#define PC1 0.42545907f      // s
#define PC2 0.21272953f      // s/2
#define PC3 0.070909845f     // s/6
#define PC4 0.017727461f     // s/24
#define PC5 0.0035454923f    // s/120
#define PC6 0.00059091538f   // s/720

__device__ __forceinline__ float estrength(float v) {
    float p = PC6;
    p = fmaf(p, v, PC5);
    p = fmaf(p, v, PC4);
    p = fmaf(p, v, PC3);
    p = fmaf(p, v, PC2);
    p = fmaf(p, v, PC1);
    p = fmaf(p, v, PC0);
    return p;
}

__global__ __launch_bounds__(256, 4) void smartorn_phase1(
    const float* __restrict__ x,       // (B, N)
    const float* __restrict__ pos,     // (N, 3)
    const float* __restrict__ indir,   // (N, 3)
    const float* __restrict__ outdir,  // (N, 3)
    float* __restrict__ part)          // (NSLAB, B, N)
{
    __shared__ float4 srec[IPB * 4];           // 4 KB: 64 B per i-record
    __shared__ float  sacc[4][NB][JTILE];      // 32 KB: per-wave partials

    const int bI   = blockIdx.x;
    const int jt   = bI >> 6;    // 0..15  j-tile
    const int is   = bI & 63;    // 0..63  i-slab
    const int tid  = threadIdx.x;
    const int lane = tid & 63;
    const int w    = __builtin_amdgcn_readfirstlane(tid >> 6);

    // ---- stage the block's 64 i-records (thread t -> record t/4, quad t%4) ----
    {
        const int r  = tid >> 2;
        const int q  = tid & 3;
        const int gi = is * IPB + r;
        float4 v;
        if (q == 0)
            v = make_float4(pos[gi * 3 + 0], pos[gi * 3 + 1], pos[gi * 3 + 2],
                            outdir[gi * 3 + 0]);
        else if (q == 1)
            v = make_float4(outdir[gi * 3 + 1], outdir[gi * 3 + 2],
                            x[0 * NN + gi], x[1 * NN + gi]);
        else if (q == 2)
            v = make_float4(x[2 * NN + gi], x[3 * NN + gi],
                            x[4 * NN + gi], x[5 * NN + gi]);
        else
            v = make_float4(x[6 * NN + gi], x[7 * NN + gi], 0.f, 0.f);
        srec[r * 4 + q] = v;
    }

    // ---- per-lane j-state: RJ receivers ----
    float pjx[RJ], pjy[RJ], pjz[RJ], inx[RJ], iny[RJ], inz[RJ];
#pragma unroll
    for (int r = 0; r < RJ; ++r) {
        const int jg = jt * JTILE + r * 64 + lane;
        pjx[r] = pos[jg * 3 + 0];
        pjy[r] = pos[jg * 3 + 1];
        pjz[r] = pos[jg * 3 + 2];
        inx[r] = indir[jg * 3 + 0];
        iny[r] = indir[jg * 3 + 1];
        inz[r] = indir[jg * 3 + 2];
    }

    __syncthreads();

    f2 acc[RJ][4];
#pragma unroll
    for (int r = 0; r < RJ; ++r)
#pragma unroll
        for (int k = 0; k < 4; ++k) acc[r][k] = (f2){0.f, 0.f};

    const float4* S = &srec[w * IPW * 4];   // wave-uniform base -> broadcast reads

#pragma unroll 2
    for (int s = 0; s < IPW; ++s) {
        const float4 q0 = S[s * 4 + 0];   // {px, py, pz, ox}
        const float4 q1 = S[s * 4 + 1];   // {oy, oz, x0, x1}
        const float4 q2 = S[s * 4 + 2];   // {x2, x3, x4, x5}
        const float4 q3 = S[s * 4 + 3];   // {x6, x7, -, -}

#pragma unroll
        for (int r = 0; r < RJ; ++r) {
            const float dx = pjx[r] - q0.x;
            const float dy = pjy[r] - q0.y;
            const float dz = pjz[r] - q0.z;
            float n2 = fmaf(dx, dx, fmaf(dy, dy, dz * dz));
            n2 = fmaxf(n2, 1e-5f);
            const float inv = rsqrtf(n2);
            const float da = fmaf(dx, q0.w, fmaf(dy, q1.x, dz * q1.y)) * inv;
            const float db = fmaf(dx, inx[r], fmaf(dy, iny[r], dz * inz[r])) * inv;
            const float g = estrength(da) * estrength(db);   // SC folded in
            const f2 gv = {g, g};
            acc[r][0] = __builtin_elementwise_fma((f2){q1.z, q1.w}, gv, acc[r][0]);
            acc[r][1] = __builtin_elementwise_fma((f2){q2.x, q2.y}, gv, acc[r][1]);
            acc[r][2] = __builtin_elementwise_fma((f2){q2.z, q2.w}, gv, acc[r][2]);
            acc[r][3] = __builtin_elementwise_fma((f2){q3.x, q3.y}, gv, acc[r][3]);
        }
    }

    // ---- dump per-wave partials (stride-1 across lanes: conflict-free) ----
#pragma unroll
    for (int r = 0; r < RJ; ++r) {
        const int jp = r * 64 + lane;
#pragma unroll
        for (int k = 0; k < 4; ++k) {
            sacc[w][2 * k + 0][jp] = acc[r][k].x;
            sacc[w][2 * k + 1][jp] = acc[r][k].y;
        }
    }
    __syncthreads();

    // ---- cross-wave reduce, write slab (coalesced 256-wide) ----
#pragma unroll
    for (int b = 0; b < NB; ++b) {
        const float s = sacc[0][b][tid] + sacc[1][b][tid] +
                        sacc[2][b][tid] + sacc[3][b][tid];
        part[(is * NB + b) * NN + jt * JTILE + tid] = s;
    }
}

__global__ __launch_bounds__(256) void smartorn_phase2(
    const float* __restrict__ part,    // (NSLAB, B, N)
    const float* __restrict__ power,   // (N)
    const float* __restrict__ bias,    // (N)
    float* __restrict__ out)           // (B, N)
{
    const int t = blockIdx.x * 256 + threadIdx.x;   // 0 .. B*N-1
    const int j = t & (NN - 1);
    const int b = t >> 12;
    float s = 0.f;
#pragma unroll 16
    for (int is = 0; is < NSLAB; ++is)
        s += part[(is * NB + b) * NN + j];
    const float v = fmaf(s, power[j], -bias[j]);
    out[t] = v > 0.f ? v : expm1f(v);
}

extern "C" void kernel_launch(void* const* d_in, const int* in_sizes, int n_in,
                              void* d_out, int out_size, void* d_ws, size_t ws_size,
                              hipStream_t stream) {
    const float* x      = (const float*)d_in[0];
    const float* pos    = (const float*)d_in[1];
    const float* indir  = (const float*)d_in[2];
    const float* outdir = (const float*)d_in[3];
    const float* power  = (const float*)d_in[4];
    const float* bias   = (const float*)d_in[5];
    float* part = (float*)d_ws;          // NSLAB*B*N*4 = 8 MiB
    float* out  = (float*)d_out;

    dim3 block(256);
    hipLaunchKernelGGL(smartorn_phase1, dim3((NN / JTILE) * NSLAB), block, 0, stream,
                       x, pos, indir, outdir, part);
    hipLaunchKernelGGL(smartorn_phase2, dim3((NB * NN) / 256), block, 0, stream,
                       part, power, bias, out);
}

// Round 9
// 83.131 us; speedup vs baseline: 1.2141x; 1.0064x over previous
//
#include <hip/hip_runtime.h>
#include <hip/hip_fp16.h>

// smartorn layer: out[b,j] = elu(power[j] * sum_i x[b,i]*gate(i,j) - bias[j])
// gate(i,j) = strength(dpb . outdir_i) * strength(dpb . indir_j)
//   dp = pos_j - pos_i, dpb = dp / sqrt(max(|dp|^2, 1e-5))
//   strength(v) = (exp(v) - e^-1) / (e - e^-1)
//
// R7 post-mortem: exp->poly neutral => p1 is VALU-ISSUE-bound (~12.5us), not
// transcendental-bound. Harness floor ~65-68us (256MiB ws poison). R9 = R8
// with the compile fix: ROCm 7.2 has no __hmin2 -> packed min implemented via
// __builtin_elementwise_min on _Float16x2 (lowers to v_pk_min_f16).
// Gate computed in PACKED f16 (VOP3P = 2 j's per instr), B=8 accumulation in
// exact f32 v_pk_fma. inv = min(h2rsqrt(n2), 1/sqrt(1e-5)) is algebraically
// the reference clamp and inf/denorm-safe (i==j: dar=0 -> g=(1-C1)^2).
// SC folded into staged x. Structure otherwise R5: 4 j/lane, broadcast
// ds_read_b128 i-records, 64 deterministic i-slabs, no fences, no atomics.

#define NN 4096
#define NB 8
#define RJ 4                 // j per lane (2 packed f16 pairs)
#define JTILE 256            // j per block (= 64 lanes * RJ)
#define IPB 64               // i per block chunk
#define IPW 16               // i per wave (4 waves split the chunk)
#define NSLAB (NN / IPB)     // 64 deterministic i-slabs

#define SC 0.18101541533756566f   // 1/(e - e^-1)^2, folded into staged x
#define C1F 0.36787944117144233f  // e^-1
#define INVMAXF 316.2277660f      // 1/sqrt(1e-5)
#define LOG2EF 1.4426950408889634f

typedef __attribute__((ext_vector_type(2))) float f2;
typedef _Float16 hv2 __attribute__((ext_vector_type(2)));

__device__ __forceinline__ float dup_h2(float f) {
    __half2 h2 = __half2half2(__float2half(f));
    return __builtin_bit_cast(float, h2);
}
__device__ __forceinline__ __half2 bch2(float f) {
    return __builtin_bit_cast(__half2, f);
}
__device__ __forceinline__ __half2 hmin2(__half2 a, __half2 b) {
    hv2 av = __builtin_bit_cast(hv2, a);
    hv2 bv = __builtin_bit_cast(hv2, b);
    hv2 rv = __builtin_elementwise_min(av, bv);   // v_pk_min_f16
    return __builtin_bit_cast(__half2, rv);
}

__global__ __launch_bounds__(256, 4) void smartorn_phase1(
    const float* __restrict__ x,       // (B, N)
    const float* __restrict__ pos,     // (N, 3)
    const float* __restrict__ indir,   // (N, 3)
    const float* __restrict__ outdir,  // (N, 3)
    float* __restrict__ part)          // (NSLAB, B, N)
{
    __shared__ float4 srec[IPB * 4];           // 4 KB: 64 B per i-record
    __shared__ float  sacc[4][NB][JTILE];      // 32 KB: per-wave partials

    const int bI   = blockIdx.x;
    const int jt   = bI >> 6;    // 0..15  j-tile
    const int is   = bI & 63;    // 0..63  i-slab
    const int tid  = threadIdx.x;
    const int lane = tid & 63;
    const int w    = __builtin_amdgcn_readfirstlane(tid >> 6);

    // ---- stage 64 i-records: geometry as duplicated f16x2, x pre-scaled by SC
    {
        const int r  = tid >> 2;
        const int q  = tid & 3;
        const int gi = is * IPB + r;
        float4 v;
        if (q == 0)
            v = make_float4(dup_h2(pos[gi * 3 + 0]), dup_h2(pos[gi * 3 + 1]),
                            dup_h2(pos[gi * 3 + 2]), dup_h2(outdir[gi * 3 + 0]));
        else if (q == 1)
            v = make_float4(dup_h2(outdir[gi * 3 + 1]), dup_h2(outdir[gi * 3 + 2]),
                            x[0 * NN + gi] * SC, x[1 * NN + gi] * SC);
        else if (q == 2)
            v = make_float4(x[2 * NN + gi] * SC, x[3 * NN + gi] * SC,
                            x[4 * NN + gi] * SC, x[5 * NN + gi] * SC);
        else
            v = make_float4(x[6 * NN + gi] * SC, x[7 * NN + gi] * SC, 0.f, 0.f);
        srec[r * 4 + q] = v;
    }

    // ---- per-lane j-state: RJ=4 receivers as 2 f16x2 packs (low=r even) ----
    __half2 pjx2[2], pjy2[2], pjz2[2], inx2[2], iny2[2], inz2[2];
#pragma unroll
    for (int pk = 0; pk < 2; ++pk) {
        const int jl = jt * JTILE + (2 * pk + 0) * 64 + lane;
        const int jh = jt * JTILE + (2 * pk + 1) * 64 + lane;
        pjx2[pk] = __halves2half2(__float2half(pos[jl * 3 + 0]), __float2half(pos[jh * 3 + 0]));
        pjy2[pk] = __halves2half2(__float2half(pos[jl * 3 + 1]), __float2half(pos[jh * 3 + 1]));
        pjz2[pk] = __halves2half2(__float2half(pos[jl * 3 + 2]), __float2half(pos[jh * 3 + 2]));
        inx2[pk] = __halves2half2(__float2half(indir[jl * 3 + 0]), __float2half(indir[jh * 3 + 0]));
        iny2[pk] = __halves2half2(__float2half(indir[jl * 3 + 1]), __float2half(indir[jh * 3 + 1]));
        inz2[pk] = __halves2half2(__float2half(indir[jl * 3 + 2]), __float2half(indir[jh * 3 + 2]));
    }

    __syncthreads();

    f2 acc[RJ][4];
#pragma unroll
    for (int r = 0; r < RJ; ++r)
#pragma unroll
        for (int k = 0; k < 4; ++k) acc[r][k] = (f2){0.f, 0.f};

    const __half2 invmax2 = __float2half2_rn(INVMAXF);
    const __half2 log2e2  = __float2half2_rn(LOG2EF);
    const __half2 c12     = __float2half2_rn(C1F);

    const float4* S = &srec[w * IPW * 4];   // wave-uniform base -> broadcast reads

#pragma unroll 2
    for (int s = 0; s < IPW; ++s) {
        const float4 q0 = S[s * 4 + 0];   // {px2, py2, pz2, ox2}
        const float4 q1 = S[s * 4 + 1];   // {oy2, oz2, x0s, x1s}
        const float4 q2 = S[s * 4 + 2];   // {x2s, x3s, x4s, x5s}
        const float4 q3 = S[s * 4 + 3];   // {x6s, x7s, -, -}

        const __half2 px2 = bch2(q0.x), py2 = bch2(q0.y);
        const __half2 pz2 = bch2(q0.z), ox2 = bch2(q0.w);
        const __half2 oy2 = bch2(q1.x), oz2 = bch2(q1.y);

        const f2 x01 = {q1.z, q1.w};
        const f2 x23 = {q2.x, q2.y};
        const f2 x45 = {q2.z, q2.w};
        const f2 x67 = {q3.x, q3.y};

#pragma unroll
        for (int pk = 0; pk < 2; ++pk) {
            const __half2 dx = __hsub2(pjx2[pk], px2);
            const __half2 dy = __hsub2(pjy2[pk], py2);
            const __half2 dz = __hsub2(pjz2[pk], pz2);
            const __half2 n2 = __hfma2(dx, dx, __hfma2(dy, dy, __hmul2(dz, dz)));
            // inv = min(rsqrt(n2), 1/sqrt(1e-5)) == 1/sqrt(max(n2,1e-5)); inf-safe
            const __half2 inv = hmin2(h2rsqrt(n2), invmax2);
            const __half2 dar = __hfma2(dx, ox2, __hfma2(dy, oy2, __hmul2(dz, oz2)));
            const __half2 dbr = __hfma2(dx, inx2[pk],
                                 __hfma2(dy, iny2[pk], __hmul2(dz, inz2[pk])));
            const __half2 ea = h2exp2(__hmul2(__hmul2(dar, inv), log2e2));
            const __half2 eb = h2exp2(__hmul2(__hmul2(dbr, inv), log2e2));
            const __half2 g2 = __hmul2(__hsub2(ea, c12), __hsub2(eb, c12));

            const float glo = __low2float(g2);    // j-group r = 2*pk
            const float ghi = __high2float(g2);   // j-group r = 2*pk+1
            const f2 gl = {glo, glo};
            const f2 gh = {ghi, ghi};
            acc[2 * pk + 0][0] = __builtin_elementwise_fma(x01, gl, acc[2 * pk + 0][0]);
            acc[2 * pk + 0][1] = __builtin_elementwise_fma(x23, gl, acc[2 * pk + 0][1]);
            acc[2 * pk + 0][2] = __builtin_elementwise_fma(x45, gl, acc[2 * pk + 0][2]);
            acc[2 * pk + 0][3] = __builtin_elementwise_fma(x67, gl, acc[2 * pk + 0][3]);
            acc[2 * pk + 1][0] = __builtin_elementwise_fma(x01, gh, acc[2 * pk + 1][0]);
            acc[2 * pk + 1][1] = __builtin_elementwise_fma(x23, gh, acc[2 * pk + 1][1]);
            acc[2 * pk + 1][2] = __builtin_elementwise_fma(x45, gh, acc[2 * pk + 1][2]);
            acc[2 * pk + 1][3] = __builtin_elementwise_fma(x67, gh, acc[2 * pk + 1][3]);
        }
    }

    // ---- dump per-wave partials (stride-1 across lanes: conflict-free) ----
#pragma unroll
    for (int r = 0; r < RJ; ++r) {
        const int jp = r * 64 + lane;
#pragma unroll
        for (int k = 0; k < 4; ++k) {
            sacc[w][2 * k + 0][jp] = acc[r][k].x;
            sacc[w][2 * k + 1][jp] = acc[r][k].y;
        }
    }
    __syncthreads();

    // ---- cross-wave reduce, write slab (coalesced 256-wide) ----
#pragma unroll
    for (int b = 0; b < NB; ++b) {
        const float s = sacc[0][b][tid] + sacc[1][b][tid] +
                        sacc[2][b][tid] + sacc[3][b][tid];
        part[(is * NB + b) * NN + jt * JTILE + tid] = s;
    }
}

__global__ __launch_bounds__(256) void smartorn_phase2(
    const float* __restrict__ part,    // (NSLAB, B, N)
    const float* __restrict__ power,   // (N)
    const float* __restrict__ bias,    // (N)
    float* __restrict__ out)           // (B, N)
{
    const int t = blockIdx.x * 256 + threadIdx.x;   // 0 .. B*N-1
    const int j = t & (NN - 1);
    const int b = t >> 12;
    float s = 0.f;
#pragma unroll 16
    for (int is = 0; is < NSLAB; ++is)
        s += part[(is * NB + b) * NN + j];
    const float v = fmaf(s, power[j], -bias[j]);
    out[t] = v > 0.f ? v : expm1f(v);
}

extern "C" void kernel_launch(void* const* d_in, const int* in_sizes, int n_in,
                              void* d_out, int out_size, void* d_ws, size_t ws_size,
                              hipStream_t stream) {
    const float* x      = (const float*)d_in[0];
    const float* pos    = (const float*)d_in[1];
    const float* indir  = (const float*)d_in[2];
    const float* outdir = (const float*)d_in[3];
    const float* power  = (const float*)d_in[4];
    const float* bias   = (const float*)d_in[5];
    float* part = (float*)d_ws;          // NSLAB*B*N*4 = 8 MiB
    float* out  = (float*)d_out;

    dim3 block(256);
    hipLaunchKernelGGL(smartorn_phase1, dim3((NN / JTILE) * NSLAB), block, 0, stream,
                       x, pos, indir, outdir, part);
    hipLaunchKernelGGL(smartorn_phase2, dim3((NB * NN) / 256), block, 0, stream,
                       part, power, bias, out);
}

// Round 10
// 81.575 us; speedup vs baseline: 1.2373x; 1.0191x over previous
//
#include <hip/hip_runtime.h>
#include <hip/hip_fp16.h>

// smartorn layer: out[b,j] = elu(power[j] * sum_i x[b,i]*gate(i,j) - bias[j])
// gate(i,j) = strength(dpb . outdir_i) * strength(dpb . indir_j)
//   dp = pos_j - pos_i, dpb = dp / sqrt(max(|dp|^2, 1e-5))
//   strength(v) = (exp(v) - e^-1) / (e - e^-1)
//
// R9 post-mortem: three structurally different phase1 inner loops (f32, poly,
// packed f16) all land at 83.1-83.7us => inner-loop issue count is NOT the
// binding constraint. R6 differential: p1+p2 ~15-18us inside ~83us (=~41us
// 256MiB ws-poison fill + ~25us graph/sync overhead). Remaining suspects are
// per-block invariants (j-state loads, barrier+reduce epilogue, block launch)
// and phase2's part re-read. R10 halves both: NSLAB 64->32 (512 blocks, each
// stages 128 i-records ONCE, 8KB LDS, single barrier pair) and part 8->4MiB.
// Gate stays packed f16 (2 j/instr), accumulation exact f32 v_pk_fma.
// inv = min(h2rsqrt(n2), 1/sqrt(1e-5)) == reference clamp, inf/denorm-safe.

#define NN 4096
#define NB 8
#define RJ 4                 // j per lane (2 packed f16 pairs)
#define JTILE 256            // j per block (= 64 lanes * RJ)
#define IPB 128              // i staged per block (once)
#define IPW 32               // i per wave (4 waves split the chunk)
#define NSLAB (NN / IPB)     // 32 deterministic i-slabs

#define SC 0.18101541533756566f   // 1/(e - e^-1)^2, folded into staged x
#define C1F 0.36787944117144233f  // e^-1
#define INVMAXF 316.2277660f      // 1/sqrt(1e-5)
#define LOG2EF 1.4426950408889634f

typedef __attribute__((ext_vector_type(2))) float f2;
typedef _Float16 hv2 __attribute__((ext_vector_type(2)));

__device__ __forceinline__ float dup_h2(float f) {
    __half2 h2 = __half2half2(__float2half(f));
    return __builtin_bit_cast(float, h2);
}
__device__ __forceinline__ __half2 bch2(float f) {
    return __builtin_bit_cast(__half2, f);
}
__device__ __forceinline__ __half2 hmin2(__half2 a, __half2 b) {
    hv2 av = __builtin_bit_cast(hv2, a);
    hv2 bv = __builtin_bit_cast(hv2, b);
    hv2 rv = __builtin_elementwise_min(av, bv);   // v_pk_min_f16
    return __builtin_bit_cast(__half2, rv);
}

__global__ __launch_bounds__(256, 4) void smartorn_phase1(
    const float* __restrict__ x,       // (B, N)
    const float* __restrict__ pos,     // (N, 3)
    const float* __restrict__ indir,   // (N, 3)
    const float* __restrict__ outdir,  // (N, 3)
    float* __restrict__ part)          // (NSLAB, B, N)
{
    __shared__ float4 srec[IPB * 4];           // 8 KB: 64 B per i-record
    __shared__ float  sacc[4][NB][JTILE];      // 32 KB: per-wave partials

    const int bI   = blockIdx.x;
    const int jt   = bI >> 5;    // 0..15  j-tile
    const int is   = bI & 31;    // 0..31  i-slab
    const int tid  = threadIdx.x;
    const int lane = tid & 63;
    const int w    = __builtin_amdgcn_readfirstlane(tid >> 6);

    // ---- stage 128 i-records once: geometry as dup f16x2, x pre-scaled by SC
#pragma unroll
    for (int half = 0; half < 2; ++half) {
        const int idx = half * 256 + tid;      // 0..511 float4 slots
        const int r   = idx >> 2;
        const int q   = idx & 3;
        const int gi  = is * IPB + r;
        float4 v;
        if (q == 0)
            v = make_float4(dup_h2(pos[gi * 3 + 0]), dup_h2(pos[gi * 3 + 1]),
                            dup_h2(pos[gi * 3 + 2]), dup_h2(outdir[gi * 3 + 0]));
        else if (q == 1)
            v = make_float4(dup_h2(outdir[gi * 3 + 1]), dup_h2(outdir[gi * 3 + 2]),
                            x[0 * NN + gi] * SC, x[1 * NN + gi] * SC);
        else if (q == 2)
            v = make_float4(x[2 * NN + gi] * SC, x[3 * NN + gi] * SC,
                            x[4 * NN + gi] * SC, x[5 * NN + gi] * SC);
        else
            v = make_float4(x[6 * NN + gi] * SC, x[7 * NN + gi] * SC, 0.f, 0.f);
        srec[idx] = v;
    }

    // ---- per-lane j-state: RJ=4 receivers as 2 f16x2 packs (low=r even) ----
    __half2 pjx2[2], pjy2[2], pjz2[2], inx2[2], iny2[2], inz2[2];
#pragma unroll
    for (int pk = 0; pk < 2; ++pk) {
        const int jl = jt * JTILE + (2 * pk + 0) * 64 + lane;
        const int jh = jt * JTILE + (2 * pk + 1) * 64 + lane;
        pjx2[pk] = __halves2half2(__float2half(pos[jl * 3 + 0]), __float2half(pos[jh * 3 + 0]));
        pjy2[pk] = __halves2half2(__float2half(pos[jl * 3 + 1]), __float2half(pos[jh * 3 + 1]));
        pjz2[pk] = __halves2half2(__float2half(pos[jl * 3 + 2]), __float2half(pos[jh * 3 + 2]));
        inx2[pk] = __halves2half2(__float2half(indir[jl * 3 + 0]), __float2half(indir[jh * 3 + 0]));
        iny2[pk] = __halves2half2(__float2half(indir[jl * 3 + 1]), __float2half(indir[jh * 3 + 1]));
        inz2[pk] = __halves2half2(__float2half(indir[jl * 3 + 2]), __float2half(indir[jh * 3 + 2]));
    }

    __syncthreads();

    f2 acc[RJ][4];
#pragma unroll
    for (int r = 0; r < RJ; ++r)
#pragma unroll
        for (int k = 0; k < 4; ++k) acc[r][k] = (f2){0.f, 0.f};

    const __half2 invmax2 = __float2half2_rn(INVMAXF);
    const __half2 log2e2  = __float2half2_rn(LOG2EF);
    const __half2 c12     = __float2half2_rn(C1F);

    const float4* S = &srec[w * IPW * 4];   // wave-uniform base -> broadcast reads

#pragma unroll 2
    for (int s = 0; s < IPW; ++s) {
        const float4 q0 = S[s * 4 + 0];   // {px2, py2, pz2, ox2}
        const float4 q1 = S[s * 4 + 1];   // {oy2, oz2, x0s, x1s}
        const float4 q2 = S[s * 4 + 2];   // {x2s, x3s, x4s, x5s}
        const float4 q3 = S[s * 4 + 3];   // {x6s, x7s, -, -}

        const __half2 px2 = bch2(q0.x), py2 = bch2(q0.y);
        const __half2 pz2 = bch2(q0.z), ox2 = bch2(q0.w);
        const __half2 oy2 = bch2(q1.x), oz2 = bch2(q1.y);

        const f2 x01 = {q1.z, q1.w};
        const f2 x23 = {q2.x, q2.y};
        const f2 x45 = {q2.z, q2.w};
        const f2 x67 = {q3.x, q3.y};

#pragma unroll
        for (int pk = 0; pk < 2; ++pk) {
            const __half2 dx = __hsub2(pjx2[pk], px2);
            const __half2 dy = __hsub2(pjy2[pk], py2);
            const __half2 dz = __hsub2(pjz2[pk], pz2);
            const __half2 n2 = __hfma2(dx, dx, __hfma2(dy, dy, __hmul2(dz, dz)));
            // inv = min(rsqrt(n2), 1/sqrt(1e-5)) == 1/sqrt(max(n2,1e-5)); inf-safe
            const __half2 inv = hmin2(h2rsqrt(n2), invmax2);
            const __half2 dar = __hfma2(dx, ox2, __hfma2(dy, oy2, __hmul2(dz, oz2)));
            const __half2 dbr = __hfma2(dx, inx2[pk],
                                 __hfma2(dy, iny2[pk], __hmul2(dz, inz2[pk])));
            const __half2 ea = h2exp2(__hmul2(__hmul2(dar, inv), log2e2));
            const __half2 eb = h2exp2(__hmul2(__hmul2(dbr, inv), log2e2));
            const __half2 g2 = __hmul2(__hsub2(ea, c12), __hsub2(eb, c12));

            const float glo = __low2float(g2);    // j-group r = 2*pk
            const float ghi = __high2float(g2);   // j-group r = 2*pk+1
            const f2 gl = {glo, glo};
            const f2 gh = {ghi, ghi};
            acc[2 * pk + 0][0] = __builtin_elementwise_fma(x01, gl, acc[2 * pk + 0][0]);
            acc[2 * pk + 0][1] = __builtin_elementwise_fma(x23, gl, acc[2 * pk + 0][1]);
            acc[2 * pk + 0][2] = __builtin_elementwise_fma(x45, gl, acc[2 * pk + 0][2]);
            acc[2 * pk + 0][3] = __builtin_elementwise_fma(x67, gl, acc[2 * pk + 0][3]);
            acc[2 * pk + 1][0] = __builtin_elementwise_fma(x01, gh, acc[2 * pk + 1][0]);
            acc[2 * pk + 1][1] = __builtin_elementwise_fma(x23, gh, acc[2 * pk + 1][1]);
            acc[2 * pk + 1][2] = __builtin_elementwise_fma(x45, gh, acc[2 * pk + 1][2]);
            acc[2 * pk + 1][3] = __builtin_elementwise_fma(x67, gh, acc[2 * pk + 1][3]);
        }
    }

    // ---- dump per-wave partials (stride-1 across lanes: conflict-free) ----
#pragma unroll
    for (int r = 0; r < RJ; ++r) {
        const int jp = r * 64 + lane;
#pragma unroll
        for (int k = 0; k < 4; ++k) {
            sacc[w][2 * k + 0][jp] = acc[r][k].x;
            sacc[w][2 * k + 1][jp] = acc[r][k].y;
        }
    }
    __syncthreads();

    // ---- cross-wave reduce, write slab (coalesced 256-wide) ----
#pragma unroll
    for (int b = 0; b < NB; ++b) {
        const float s = sacc[0][b][tid] + sacc[1][b][tid] +
                        sacc[2][b][tid] + sacc[3][b][tid];
        part[(is * NB + b) * NN + jt * JTILE + tid] = s;
    }
}

__global__ __launch_bounds__(256) void smartorn_phase2(
    const float* __restrict__ part,    // (NSLAB, B, N)
    const float* __restrict__ power,   // (N)
    const float* __restrict__ bias,    // (N)
    float* __restrict__ out)           // (B, N)
{
    const int t = blockIdx.x * 256 + threadIdx.x;   // 0 .. B*N-1
    const int j = t & (NN - 1);
    const int b = t >> 12;
    float s = 0.f;
#pragma unroll 16
    for (int is = 0; is < NSLAB; ++is)
        s += part[(is * NB + b) * NN + j];
    const float v = fmaf(s, power[j], -bias[j]);
    out[t] = v > 0.f ? v : expm1f(v);
}

extern "C" void kernel_launch(void* const* d_in, const int* in_sizes, int n_in,
                              void* d_out, int out_size, void* d_ws, size_t ws_size,
                              hipStream_t stream) {
    const float* x      = (const float*)d_in[0];
    const float* pos    = (const float*)d_in[1];
    const float* indir  = (const float*)d_in[2];
    const float* outdir = (const float*)d_in[3];
    const float* power  = (const float*)d_in[4];
    const float* bias   = (const float*)d_in[5];
    float* part = (float*)d_ws;          // NSLAB*B*N*4 = 4 MiB
    float* out  = (float*)d_out;

    dim3 block(256);
    hipLaunchKernelGGL(smartorn_phase1, dim3((NN / JTILE) * NSLAB), block, 0, stream,
                       x, pos, indir, outdir, part);
    hipLaunchKernelGGL(smartorn_phase2, dim3((NB * NN) / 256), block, 0, stream,
                       part, power, bias, out);
}